// Round 1
// baseline (164.783 us; speedup 1.0000x reference)
//
#include <hip/hip_runtime.h>

// Cost volume: B=4, C=32, H=256, W=256, D=9, G=8, cpg=4
// out[b,g,d,h,w] = mean_{c in group g} var(warp_l, warp_r, feat_ref)
//
// R2 redesign (VALU-bound at 80% busy, HBM at 29%):
//  - 3-tap hat weights per (d,side) computed ONCE per thread (4 VALU each,
//    using max/abs modifiers): kills the 4 cndmask tap-selects per (c,d).
//    Zeros-padding folds into zeroed taps at load time (clamped address +
//    one cndmask per tap per channel, conditions reused).
//  - Variance via Q - S^2/3: sum of squared deviations = sum(x^2) - S^2/3.
//    fr^2 hoists out of the d-loop entirely. 9 ops -> 5 per (c,d).
//  - d outer / c inner: all 28 taps resident in registers, loaded upfront
//    (latency fully overlapped), ~60-70 VGPR.
//  - channel pairs packed as float2 ext-vectors -> v_pk_{mul,add,fma}_f32.

#define B_ 4
#define C_ 32
#define H_ 256
#define W_ 256
#define D_ 9
#define G_ 8
#define CPG 4
#define HW_ (H_ * W_)

typedef float v2f __attribute__((ext_vector_type(2)));

static __device__ __forceinline__ v2f sp(float x) {
    v2f r; r.x = x; r.y = x; return r;
}

__global__ __launch_bounds__(256) void cost_volume_kernel(
    const float* __restrict__ fref,
    const float* __restrict__ fls,
    const float* __restrict__ frs,
    const float* __restrict__ disp0,
    float* __restrict__ out)
{
    // Compile-time table: d-loop is fully unrolled, these fold to literals.
    const float kRes[D_] = {-0.4f, -0.3f, -0.2f, -0.1f, 0.0f,
                             0.1f,  0.2f,  0.3f,  0.4f};

    const int bid = blockIdx.x;
    const int g = bid & (G_ - 1);
    const int t = bid >> 3;
    const int h = t & (H_ - 1);
    const int b = t >> 8;
    const int w = threadIdx.x;

    const float dbase = disp0[(unsigned)((b * H_ + h) * W_ + w)];
    const float wf = (float)w;

    // Left: x_l(d) = w + dbase + res[d], min at d=0. All 9 x_l span < 1.0,
    // so taps i0l..i0l+2 cover every d. u_l(d) = x_l - i0l = al + res[d],
    // al in [0.4, 1.4). Hat weights in t = u-1:
    //   W0 = max(0,-t), W1 = 1-|t|, W2 = max(0,t)   (exact piecewise lerp)
    const float s0 = wf + dbase;
    const int i0l = (int)floorf(s0 - 0.4f);
    const float a1l = (s0 - (float)i0l) - 1.0f;   // t_l(d) = a1l + res[d]

    // Right: x_r(d) = w - dbase - res[d], min at d=8.
    const float s1 = wf - dbase;
    const int i0r = (int)floorf(s1 - 0.4f);
    const float a1r = (s1 - (float)i0r) - 1.0f;   // t_r(d) = a1r - res[d]

    const unsigned rowbase = (unsigned)(((b * C_ + g * CPG) * HW_) + h * W_);
    const float* __restrict__ refrow = fref + rowbase;
    const float* __restrict__ lsrow  = fls  + rowbase;
    const float* __restrict__ rsrow  = frs  + rowbase;

    // All taps for the 4 channels, resident in registers. Zeros-padding:
    // OOB tap -> 0 value (clamped address keeps the load in-bounds).
    v2f tl01[3], tl23[3], tr01[3], tr23[3];
    #pragma unroll
    for (int k = 0; k < 3; ++k) {
        const int il = i0l + k;
        const bool vl = (unsigned)il < (unsigned)W_;
        const unsigned ilc = (unsigned)(il < 0 ? 0 : (il > W_ - 1 ? W_ - 1 : il));
        v2f a, c;
        a.x = vl ? lsrow[ilc] : 0.0f;
        a.y = vl ? lsrow[HW_ + ilc] : 0.0f;
        c.x = vl ? lsrow[2u * HW_ + ilc] : 0.0f;
        c.y = vl ? lsrow[3u * HW_ + ilc] : 0.0f;
        tl01[k] = a; tl23[k] = c;

        const int ir = i0r + k;
        const bool vr = (unsigned)ir < (unsigned)W_;
        const unsigned irc = (unsigned)(ir < 0 ? 0 : (ir > W_ - 1 ? W_ - 1 : ir));
        v2f e, f;
        e.x = vr ? rsrow[irc] : 0.0f;
        e.y = vr ? rsrow[HW_ + irc] : 0.0f;
        f.x = vr ? rsrow[2u * HW_ + irc] : 0.0f;
        f.y = vr ? rsrow[3u * HW_ + irc] : 0.0f;
        tr01[k] = e; tr23[k] = f;
    }

    v2f fr01, fr23;
    fr01.x = refrow[(unsigned)w];
    fr01.y = refrow[HW_ + (unsigned)w];
    fr23.x = refrow[2u * HW_ + (unsigned)w];
    fr23.y = refrow[3u * HW_ + (unsigned)w];
    // sum of fr^2 over the group: d-invariant part of Q
    const float frq = fr01.x * fr01.x + fr01.y * fr01.y
                    + fr23.x * fr23.x + fr23.y * fr23.y;

    const unsigned obase = (unsigned)(((b * G_ + g) * D_) * HW_ + h * W_ + w);

    #pragma unroll
    for (int d = 0; d < D_; ++d) {
        const float tlw = a1l + kRes[d];
        const float W0l = fmaxf(-tlw, 0.0f);
        const float W1l = 1.0f - fabsf(tlw);
        const float W2l = fmaxf(tlw, 0.0f);
        const float trw = a1r - kRes[d];
        const float W0r = fmaxf(-trw, 0.0f);
        const float W1r = 1.0f - fabsf(trw);
        const float W2r = fmaxf(trw, 0.0f);

        v2f wl01 = tl01[0] * sp(W0l) + tl01[1] * sp(W1l) + tl01[2] * sp(W2l);
        v2f wl23 = tl23[0] * sp(W0l) + tl23[1] * sp(W1l) + tl23[2] * sp(W2l);
        v2f wr01 = tr01[0] * sp(W0r) + tr01[1] * sp(W1r) + tr01[2] * sp(W2r);
        v2f wr23 = tr23[0] * sp(W0r) + tr23[1] * sp(W1r) + tr23[2] * sp(W2r);

        // sum over c of (wl^2 + wr^2), and of S^2 with S = wl + wr + fr
        v2f q  = wl01 * wl01 + wr01 * wr01 + wl23 * wl23 + wr23 * wr23;
        v2f s01 = wl01 + wr01 + fr01;
        v2f s23 = wl23 + wr23 + fr23;
        v2f s2 = s01 * s01 + s23 * s23;

        const float Q  = q.x + q.y + frq;
        const float S2 = s2.x + s2.y;
        // var = (Q_c - S_c^2/3)/3 per channel, group mean /4 => *(1/12)
        out[obase + (unsigned)d * (unsigned)HW_] =
            (Q - S2 * (1.0f / 3.0f)) * (1.0f / 12.0f);
    }
}

extern "C" void kernel_launch(void* const* d_in, const int* in_sizes, int n_in,
                              void* d_out, int out_size, void* d_ws, size_t ws_size,
                              hipStream_t stream) {
    const float* fref  = (const float*)d_in[0];
    const float* fls   = (const float*)d_in[1];
    const float* frs   = (const float*)d_in[2];
    const float* disp0 = (const float*)d_in[3];
    float* out = (float*)d_out;

    dim3 grid(B_ * H_ * G_);
    dim3 block(W_);
    cost_volume_kernel<<<grid, block, 0, stream>>>(fref, fls, frs, disp0, out);
}

// Round 2
// 161.901 us; speedup vs baseline: 1.0178x; 1.0178x over previous
//
#include <hip/hip_runtime.h>

// Cost volume: B=4, C=32, H=256, W=256, D=9, G=8, cpg=4
// out[b,g,d,h,w] = mean_{c in group g} var(warp_l, warp_r, feat_ref)
//
// R3: latency restructure. R2 halved VALU (80%->45% busy) with ZERO change
// in duration (55.5us) => not VALU-bound; bound by the serial
// disp-load -> scattered-gather global round-trips. Since disp in [0,1)
// and res in [-0.4,0.4], every tap lies in [w-2, w+2]: stage the 8
// channel-rows (4 left + 4 right, 260-wide with halo) into LDS with
// coalesced disp-INDEPENDENT loads (they overlap the disp load), then
// resolve the data-dependent taps from LDS (~120cy) instead of global
// (~500cy). Zeros-padding is baked into the staged halo. Output stores
// are nontemporal so the 75MB write stream doesn't evict LLC-resident
// inputs.

#define B_ 4
#define C_ 32
#define H_ 256
#define W_ 256
#define D_ 9
#define G_ 8
#define CPG 4
#define HW_ (H_ * W_)
#define SW_ 260   // staged row: x in [-2, W+1]

typedef float v2f __attribute__((ext_vector_type(2)));

static __device__ __forceinline__ v2f sp(float x) {
    v2f r; r.x = x; r.y = x; return r;
}

__global__ __launch_bounds__(256) void cost_volume_kernel(
    const float* __restrict__ fref,
    const float* __restrict__ fls,
    const float* __restrict__ frs,
    const float* __restrict__ disp0,
    float* __restrict__ out)
{
    const float kRes[D_] = {-0.4f, -0.3f, -0.2f, -0.1f, 0.0f,
                             0.1f,  0.2f,  0.3f,  0.4f};

    __shared__ float sL[CPG][SW_];
    __shared__ float sR[CPG][SW_];

    const int bid = blockIdx.x;
    const int g = bid & (G_ - 1);
    const int t = bid >> 3;
    const int h = t & (H_ - 1);
    const int b = t >> 8;
    const int w = threadIdx.x;

    // Issue the data-dependent seed load first; staging overlaps it.
    const float dbase = disp0[(unsigned)((b * H_ + h) * W_ + w)];

    const unsigned rowbase = (unsigned)(((b * C_ + g * CPG) * HW_) + h * W_);
    const float* __restrict__ refrow = fref + rowbase;
    const float* __restrict__ lsrow  = fls  + rowbase;
    const float* __restrict__ rsrow  = frs  + rowbase;

    // ---- disp-independent work: stage left/right rows with halo ----
    {
        const int x = w - 2;                       // covers x = -2 .. 253
        const bool v = (unsigned)x < (unsigned)W_;
        #pragma unroll
        for (int cc = 0; cc < CPG; ++cc) {
            sL[cc][w] = v ? lsrow[cc * HW_ + x] : 0.0f;
            sR[cc][w] = v ? rsrow[cc * HW_ + x] : 0.0f;
        }
        if (w < SW_ - W_) {                        // 4 threads: x = 254..257
            const int x2 = W_ - 2 + w;
            const bool v2 = x2 < W_;
            #pragma unroll
            for (int cc = 0; cc < CPG; ++cc) {
                sL[cc][W_ + w] = v2 ? lsrow[cc * HW_ + x2] : 0.0f;
                sR[cc][W_ + w] = v2 ? rsrow[cc * HW_ + x2] : 0.0f;
            }
        }
    }

    // fref at exactly w: coalesced, disp-independent
    v2f fr01, fr23;
    fr01.x = refrow[(unsigned)w];
    fr01.y = refrow[HW_ + (unsigned)w];
    fr23.x = refrow[2u * HW_ + (unsigned)w];
    fr23.y = refrow[3u * HW_ + (unsigned)w];
    const float frq = fr01.x * fr01.x + fr01.y * fr01.y
                    + fr23.x * fr23.x + fr23.y * fr23.y;

    __syncthreads();

    // ---- disp-dependent address/weight setup ----
    const float wf = (float)w;
    // Left: x_l(d) = w + dbase + res[d]; min-floor i0l = floor(s0 - 0.4).
    const float s0 = wf + dbase;
    const int i0l = (int)floorf(s0 - 0.4f);
    int relL = i0l - w;                 // expected {-1, 0}
    relL = relL < -1 ? -1 : (relL > 0 ? 0 : relL);   // LDS-safety clamp
    const float a1l = (s0 - (float)(w + relL)) - 1.0f;

    // Right: x_r(d) = w - dbase - res[d]; min-floor i0r = floor(s1 - 0.4).
    const float s1 = wf - dbase;
    const int i0r = (int)floorf(s1 - 0.4f);
    int relR = i0r - w;                 // expected {-2, -1}
    relR = relR < -2 ? -2 : (relR > -1 ? -1 : relR); // LDS-safety clamp
    const float a1r = (s1 - (float)(w + relR)) - 1.0f;

    const int baseL = w + relL + 2;     // in [1, w+2] .. max 257
    const int baseR = w + relR + 2;     // in [0, w+1] .. max 256

    // ---- gather taps from LDS (short latency, conflict-free) ----
    v2f tl01[3], tl23[3], tr01[3], tr23[3];
    #pragma unroll
    for (int k = 0; k < 3; ++k) {
        tl01[k].x = sL[0][baseL + k];
        tl01[k].y = sL[1][baseL + k];
        tl23[k].x = sL[2][baseL + k];
        tl23[k].y = sL[3][baseL + k];
        tr01[k].x = sR[0][baseR + k];
        tr01[k].y = sR[1][baseR + k];
        tr23[k].x = sR[2][baseR + k];
        tr23[k].y = sR[3][baseR + k];
    }

    const unsigned obase = (unsigned)(((b * G_ + g) * D_) * HW_ + h * W_ + w);

    #pragma unroll
    for (int d = 0; d < D_; ++d) {
        // 3-tap hat weights (exact piecewise lerp), 4 VALU per side.
        const float tlw = a1l + kRes[d];
        const float W0l = fmaxf(-tlw, 0.0f);
        const float W1l = 1.0f - fabsf(tlw);
        const float W2l = fmaxf(tlw, 0.0f);
        const float trw = a1r - kRes[d];
        const float W0r = fmaxf(-trw, 0.0f);
        const float W1r = 1.0f - fabsf(trw);
        const float W2r = fmaxf(trw, 0.0f);

        v2f wl01 = tl01[0] * sp(W0l) + tl01[1] * sp(W1l) + tl01[2] * sp(W2l);
        v2f wl23 = tl23[0] * sp(W0l) + tl23[1] * sp(W1l) + tl23[2] * sp(W2l);
        v2f wr01 = tr01[0] * sp(W0r) + tr01[1] * sp(W1r) + tr01[2] * sp(W2r);
        v2f wr23 = tr23[0] * sp(W0r) + tr23[1] * sp(W1r) + tr23[2] * sp(W2r);

        // Sum-of-squared-deviations via Q - S^2/3; fr^2 hoisted (frq).
        v2f q   = wl01 * wl01 + wr01 * wr01 + wl23 * wl23 + wr23 * wr23;
        v2f s01 = wl01 + wr01 + fr01;
        v2f s23 = wl23 + wr23 + fr23;
        v2f s2  = s01 * s01 + s23 * s23;

        const float Q  = q.x + q.y + frq;
        const float S2 = s2.x + s2.y;
        // var = (Q_c - S_c^2/3)/3 per channel, group mean /4 => *(1/12)
        const float val = (Q - S2 * (1.0f / 3.0f)) * (1.0f / 12.0f);
        __builtin_nontemporal_store(val, &out[obase + (unsigned)d * (unsigned)HW_]);
    }
}

extern "C" void kernel_launch(void* const* d_in, const int* in_sizes, int n_in,
                              void* d_out, int out_size, void* d_ws, size_t ws_size,
                              hipStream_t stream) {
    const float* fref  = (const float*)d_in[0];
    const float* fls   = (const float*)d_in[1];
    const float* frs   = (const float*)d_in[2];
    const float* disp0 = (const float*)d_in[3];
    float* out = (float*)d_out;

    dim3 grid(B_ * H_ * G_);
    dim3 block(W_);
    cost_volume_kernel<<<grid, block, 0, stream>>>(fref, fls, frs, disp0, out);
}